// Round 3
// baseline (637.627 us; speedup 1.0000x reference)
//
#include <hip/hip_runtime.h>

typedef __bf16 bf16;
typedef __bf16 bf16x4 __attribute__((ext_vector_type(4)));
typedef __bf16 bf16x8 __attribute__((ext_vector_type(8)));
typedef float f32x4 __attribute__((ext_vector_type(4)));
typedef float floatx4 __attribute__((ext_vector_type(4)));

#define S 96
#define DIN 768
#define DOUT 256
#define MROWS 73728  // 8*96*96

__device__ static inline void async16(const bf16* g, bf16* l) {
    __builtin_amdgcn_global_load_lds(
        (const __attribute__((address_space(1))) void*)g,
        (__attribute__((address_space(3))) void*)l,
        16, 0, 0);
}

// ---------------------------------------------------------------------------
// gether1: X = gether(H) + H  (coefficient 2 on center row). fp32 in, bf16 out
// grid (8*S, 2); XCD-bijective swizzle (neighbor rows L2-resident).
// ---------------------------------------------------------------------------
__global__ __launch_bounds__(256) void k_gether1(
    const float* __restrict__ H, const float* __restrict__ Asim,
    const float* __restrict__ Tsim, const float* __restrict__ Adj,
    bf16* __restrict__ X)
{
    __shared__ float adjs[S];
    __shared__ float ts[S];
    __shared__ float diagf[DIN];
    int bx = blockIdx.x;
    bx = (bx & 7) * (gridDim.x >> 3) + (bx >> 3);  // 768 % 8 == 0: bijective
    int b = bx / S, l = bx % S;
    int tid = threadIdx.x;
    long row0 = (long)(b * S + l) * S;
    if (tid < S) {
        adjs[tid] = Adj[(b * S + l) * S + tid];
        ts[tid]   = Tsim[b * S + tid];
    }
    for (int i = tid; i < DIN / 4; i += 256)
        *(f32x4*)&diagf[i * 4] = *(const f32x4*)&H[(row0 + l) * DIN + i * 4];
    float a_up = (l > 0)     ? Asim[b * S + l - 1] : 0.f;
    float a_dn = (l < S - 1) ? Asim[b * S + l + 1] : 0.f;
    long du = (l > 0)     ? -(long)S * DIN : 0;
    long dd = (l < S - 1) ?  (long)S * DIN : 0;
    __syncthreads();

    int lane = tid & 63, wv = tid >> 6;
    int k0 = blockIdx.y * (S / 2);
    for (int k = k0 + wv; k < k0 + S / 2; k += 4) {
        float tl = (k > 0)     ? ts[k - 1] : 0.f;
        float tr = (k < S - 1) ? ts[k + 1] : 0.f;
        long  dl = (k > 0)     ? -(long)DIN : 0;
        long  dr = (k < S - 1) ?  (long)DIN : 0;
        float aj = adjs[k];
        const float* hrow = H + (row0 + k) * DIN;
        bf16* xrow = X + (row0 + k) * DIN;
#pragma unroll
        for (int c = 0; c < 3; ++c) {
            int col = (lane + c * 64) * 4;
            const float* hc = hrow + col;
            f32x4 vc = *(const f32x4*)hc;
            f32x4 vl = *(const f32x4*)(hc + dl);
            f32x4 vr = *(const f32x4*)(hc + dr);
            f32x4 vu = *(const f32x4*)(hc + du);
            f32x4 vd = *(const f32x4*)(hc + dd);
            bf16x4 o;
#pragma unroll
            for (int j = 0; j < 4; ++j) {
                float v = 2.f * vc[j] + aj * diagf[col + j]
                        + tl * vl[j] + tr * vr[j]
                        + a_up * vu[j] + a_dn * vd[j];
                o[j] = (bf16)v;
            }
            *(bf16x4*)&xrow[col] = o;
        }
    }
}

// ---------------------------------------------------------------------------
// gether2: sources are h1 = relu(g1 * y * invr) reconstructed on the fly.
// grid (8*S, 2); same XCD swizzle.
// ---------------------------------------------------------------------------
__global__ __launch_bounds__(256) void k_gether2(
    const bf16* __restrict__ Y, const float* __restrict__ INV,
    const float* __restrict__ G1, const float* __restrict__ Asim,
    const float* __restrict__ Tsim, const float* __restrict__ Adj,
    bf16* __restrict__ X)
{
    __shared__ float adjs[S];
    __shared__ float ts[S];
    __shared__ float diagf[DIN];
    __shared__ float g1s[DIN];
    int bx = blockIdx.x;
    bx = (bx & 7) * (gridDim.x >> 3) + (bx >> 3);
    int b = bx / S, l = bx % S;
    int tid = threadIdx.x;
    long row0 = (long)(b * S + l) * S;
    for (int i = tid; i < DIN; i += 256) g1s[i] = G1[i];
    __syncthreads();
    if (tid < S) {
        adjs[tid] = Adj[(b * S + l) * S + tid];
        ts[tid]   = Tsim[b * S + tid];
        float iv = INV[row0 + l];
        bf16x8 yv = *(const bf16x8*)&Y[(row0 + l) * DIN + tid * 8];
#pragma unroll
        for (int j = 0; j < 8; ++j) {
            float v = g1s[tid * 8 + j] * (float)yv[j] * iv;
            diagf[tid * 8 + j] = v > 0.f ? v : 0.f;
        }
    }
    float a_up = (l > 0)     ? Asim[b * S + l - 1] : 0.f;
    float a_dn = (l < S - 1) ? Asim[b * S + l + 1] : 0.f;
    long du = (l > 0)     ? -(long)S * DIN : 0;
    long dd = (l < S - 1) ?  (long)S * DIN : 0;
    int ou = (l > 0) ? -S : 0;
    int od = (l < S - 1) ? S : 0;
    __syncthreads();

    int lane = tid & 63, wv = tid >> 6;
    int k0 = blockIdx.y * (S / 2);
    for (int k = k0 + wv; k < k0 + S / 2; k += 4) {
        float tl = (k > 0)     ? ts[k - 1] : 0.f;
        float tr = (k < S - 1) ? ts[k + 1] : 0.f;
        int   ol = (k > 0)     ? -1 : 0;
        int   orr = (k < S - 1) ? 1 : 0;
        float aj = adjs[k];
        float ivc = INV[row0 + k];
        float ivl = INV[row0 + k + ol];
        float ivr = INV[row0 + k + orr];
        float ivu = INV[row0 + k + ou];
        float ivd = INV[row0 + k + od];
        const bf16* yrow = Y + (row0 + k) * DIN;
        bf16* xrow = X + (row0 + k) * DIN;
#pragma unroll
        for (int c = 0; c < 3; ++c) {
            int col = (lane + c * 64) * 4;
            const bf16* yc = yrow + col;
            bf16x4 vc = *(const bf16x4*)yc;
            bf16x4 vl = *(const bf16x4*)(yc + (long)ol * DIN);
            bf16x4 vr = *(const bf16x4*)(yc + (long)orr * DIN);
            bf16x4 vu = *(const bf16x4*)(yc + du);
            bf16x4 vd = *(const bf16x4*)(yc + dd);
            bf16x4 o;
#pragma unroll
            for (int j = 0; j < 4; ++j) {
                float g = g1s[col + j];
                float hc_ = g * (float)vc[j] * ivc; hc_ = hc_ > 0.f ? hc_ : 0.f;
                float hl_ = g * (float)vl[j] * ivl; hl_ = hl_ > 0.f ? hl_ : 0.f;
                float hr_ = g * (float)vr[j] * ivr; hr_ = hr_ > 0.f ? hr_ : 0.f;
                float hu_ = g * (float)vu[j] * ivu; hu_ = hu_ > 0.f ? hu_ : 0.f;
                float hd_ = g * (float)vd[j] * ivd; hd_ = hd_ > 0.f ? hd_ : 0.f;
                float v = 2.f * hc_ + aj * diagf[col + j]
                        + tl * hl_ + tr * hr_ + a_up * hu_ + a_dn * hd_;
                o[j] = (bf16)v;
            }
            *(bf16x4*)&xrow[col] = o;
        }
    }
}

// ---------------------------------------------------------------------------
// GEMM1: Y1[M x 768] = X @ W1T^T + b1 (bf16), ssq atomics.
// THIS ROUND: full 256x256/BK=64 8-wave phase schedule (m201 structure).
//  - 512 thr = 8 waves (2 row x 4 col), per-wave output 128x64, acc[8][4].
//  - LDS 128KB: A/B [2][256][64] bf16, chunk-XOR swizzle (c ^= row&7):
//    8 lanes per 16B bank-group on ds_read_b128 = conflict-free.
//    global_load_lds dest stays linear; SOURCE chunk pre-swizzled (rule 21).
//  - 4 phases per K-tile: {8 ds_read_b128 | 2 stage loads | barrier |
//    lgkm0+sched_barrier | setprio(1) 16 MFMA setprio(0) | counted vmcnt |
//    barrier}. Stage order B0,B1|B2,B3|A0,A2|A1,A3 makes the tile-boundary
//    wait vmcnt(2): the 6 oldest outstanding loads are exactly what phase 0
//    needs; A1,A3 (2 newest) are only read in phase 1, guarded by a second
//    vmcnt(2) at end of phase 0. vmcnt never drains to 0 mid-loop (T4).
// ---------------------------------------------------------------------------
__global__ __launch_bounds__(512, 2) void k_gemm1(
    const bf16* __restrict__ Xm, const bf16* __restrict__ WT,
    const float* __restrict__ bias, bf16* __restrict__ Y,
    float* __restrict__ ssq)
{
    constexpr int K = 768, N = 768;
    constexpr int NTILE = K / 64;  // 12
    __shared__ __align__(16) bf16 As[2][256 * 64];
    __shared__ __align__(16) bf16 Bs[2][256 * 64];
    int t = threadIdx.x;
    int wg = blockIdx.x;
    wg = (wg & 7) * (gridDim.x >> 3) + (wg >> 3);  // 864 = 8*108: bijective
    int colBase = (wg % 3) * 256;                  // col fastest within XCD
    int rowBase = (wg / 3) * 256;
    int lane = t & 63, w = t >> 6;
    int quad = lane >> 4, l16 = lane & 15;
    int wr = w >> 2, wc = w & 3;                   // 2 x 4 waves

    floatx4 acc[8][4];
#pragma unroll
    for (int i = 0; i < 8; ++i)
#pragma unroll
        for (int j = 0; j < 4; ++j) acc[i][j] = (floatx4)0.f;

    // staging: sub-stage s covers rows [s*64, s*64+64); thread t -> row tr,
    // LDS chunk (t&7); global chunk pre-swizzled gc = (t&7) ^ (row&7).
    int tr = t >> 3;
    int gc = (t & 7) ^ (tr & 7);
    const bf16* gA = Xm + (size_t)(rowBase + tr) * K + gc * 8;
    const bf16* gB = WT + (size_t)(colBase + tr) * K + gc * 8;
    int ldst = t * 8;

    auto stageA = [&](int b, int s, int kt) {
        async16(gA + (size_t)s * 64 * K + kt * 64, &As[b][s * 4096 + ldst]);
    };
    auto stageB = [&](int b, int s, int kt) {
        async16(gB + (size_t)s * 64 * K + kt * 64, &Bs[b][s * 4096 + ldst]);
    };

    // prologue: tile 0, order B0 B1 B2 B3 A0 A2 A1 A3
    stageB(0, 0, 0); stageB(0, 1, 0); stageB(0, 2, 0); stageB(0, 3, 0);
    stageA(0, 0, 0); stageA(0, 2, 0); stageA(0, 1, 0); stageA(0, 3, 0);
    asm volatile("s_waitcnt vmcnt(2)" ::: "memory");
    __builtin_amdgcn_s_barrier();

    int swz = l16 & 7;
    int cK0 = (quad ^ swz) * 8;         // chunk offset (elems), k-step 0
    int cK1 = ((quad + 4) ^ swz) * 8;   // k-step 1

    for (int tt = 0; tt < NTILE; ++tt) {
        int cur = tt & 1;
        int nb = cur ^ 1;
        bool more = (tt + 1 < NTILE);
        const bf16* aB = &As[cur][(wr * 128 + l16) * 64];
        const bf16* bB = &Bs[cur][(wc * 64 + l16) * 64];
#pragma unroll
        for (int p = 0; p < 4; ++p) {
            const int ihalf = p & 1;
            const int co = (p >> 1) ? cK1 : cK0;
            bf16x8 af[4], bfr[4];
#pragma unroll
            for (int ii = 0; ii < 4; ++ii)
                af[ii] = *(const bf16x8*)(aB + (ihalf * 4 + ii) * 1024 + co);
#pragma unroll
            for (int j = 0; j < 4; ++j)
                bfr[j] = *(const bf16x8*)(bB + j * 1024 + co);
            if (more) {
                if (p == 0) { stageB(nb, 0, tt + 1); stageB(nb, 1, tt + 1); }
                if (p == 1) { stageB(nb, 2, tt + 1); stageB(nb, 3, tt + 1); }
                if (p == 2) { stageA(nb, 0, tt + 1); stageA(nb, 2, tt + 1); }
                if (p == 3) { stageA(nb, 1, tt + 1); stageA(nb, 3, tt + 1); }
            }
            __builtin_amdgcn_s_barrier();
            asm volatile("s_waitcnt lgkmcnt(0)" ::: "memory");
            __builtin_amdgcn_sched_barrier(0);
            __builtin_amdgcn_s_setprio(1);
#pragma unroll
            for (int ii = 0; ii < 4; ++ii)
#pragma unroll
                for (int j = 0; j < 4; ++j)
                    acc[ihalf * 4 + ii][j] = __builtin_amdgcn_mfma_f32_16x16x32_bf16(
                        af[ii], bfr[j], acc[ihalf * 4 + ii][j], 0, 0, 0);
            __builtin_amdgcn_s_setprio(0);
            if (p == 0) {
                if (more) asm volatile("s_waitcnt vmcnt(2)" ::: "memory");
                else      asm volatile("s_waitcnt vmcnt(0)" ::: "memory");
            }
            if (p == 3 && more) asm volatile("s_waitcnt vmcnt(2)" ::: "memory");
            __builtin_amdgcn_s_barrier();
        }
    }

    float bv[4];
#pragma unroll
    for (int j = 0; j < 4; ++j)
        bv[j] = bias[colBase + wc * 64 + j * 16 + l16];
#pragma unroll
    for (int i = 0; i < 8; ++i) {
#pragma unroll
        for (int r = 0; r < 4; ++r) {
            int row = rowBase + wr * 128 + i * 16 + quad * 4 + r;
            bf16* yp = Y + (size_t)row * N + colBase + wc * 64 + l16;
            float s = 0.f;
#pragma unroll
            for (int j = 0; j < 4; ++j) {
                float v = acc[i][j][r] + bv[j];
                s += v * v;
                yp[j * 16] = (bf16)v;
            }
            s += __shfl_xor(s, 1);
            s += __shfl_xor(s, 2);
            s += __shfl_xor(s, 4);
            s += __shfl_xor(s, 8);
            if (l16 == 0) atomicAdd(&ssq[row], s);
        }
    }
}

// ---------------------------------------------------------------------------
// GEMM2 fused: out[M x 256] = relu(g2 * t5norm(X2 @ W2T^T + b2)) directly.
// Block covers 128 rows x ALL 256 cols; 3-buf counted vmcnt (r2 version).
// ---------------------------------------------------------------------------
__global__ __launch_bounds__(256, 2) void k_gemm2f(
    const bf16* __restrict__ Xm, const bf16* __restrict__ WT,
    const float* __restrict__ bias, const float* __restrict__ G2,
    float* __restrict__ out)
{
    constexpr int K = 768, N = 256;
    constexpr int NT = K / 32;  // 24
    __shared__ __align__(16) bf16 As[3][128 * 32];
    __shared__ __align__(16) bf16 Bs[3][256 * 32];
    __shared__ float ssqs[2][128];
    int t = threadIdx.x;
    int rowBase = blockIdx.x * 128;
    int lane = t & 63, w = t >> 6;
    int quad = lane >> 4, l16 = lane & 15;
    int wr = w >> 1, wc = w & 1;

    floatx4 acc[4][8];
#pragma unroll
    for (int i = 0; i < 4; ++i)
#pragma unroll
        for (int j = 0; j < 8; ++j) acc[i][j] = (floatx4)0.f;

    int chunk = (t & 3) ^ ((t >> 3) & 3);
    const bf16* gA = Xm + (size_t)(rowBase + (t >> 2)) * K + chunk * 8;
    const bf16* gB = WT + (size_t)(t >> 2) * K + chunk * 8;
    int l8 = t * 8;

    auto stage = [&](int buf, int kk) {
        async16(gA + kk, &As[buf][l8]);
        async16(gA + kk + 64 * K, &As[buf][l8 + 2048]);
        async16(gB + kk, &Bs[buf][l8]);
        async16(gB + kk + 64 * K, &Bs[buf][l8 + 2048]);
        async16(gB + kk + 128 * K, &Bs[buf][l8 + 4096]);
        async16(gB + kk + 192 * K, &Bs[buf][l8 + 6144]);
    };

    stage(0, 0);
    stage(1, 32);
    for (int tt = 0; tt < NT; ++tt) {
        if (tt + 1 < NT) asm volatile("s_waitcnt vmcnt(6)" ::: "memory");
        else             asm volatile("s_waitcnt vmcnt(0)" ::: "memory");
        __builtin_amdgcn_s_barrier();
        int cur = tt % 3;
        bf16x8 af[4], bfr[8];
#pragma unroll
        for (int i = 0; i < 4; ++i) {
            int ra = wr * 64 + i * 16 + l16;
            af[i] = *(const bf16x8*)&As[cur][ra * 32 + (quad ^ ((ra >> 1) & 3)) * 8];
        }
#pragma unroll
        for (int j = 0; j < 8; ++j) {
            int rb = wc * 128 + j * 16 + l16;
            bfr[j] = *(const bf16x8*)&Bs[cur][rb * 32 + (quad ^ ((rb >> 1) & 3)) * 8];
        }
        if (tt + 2 < NT) stage((tt + 2) % 3, (tt + 2) * 32);
#pragma unroll
        for (int i = 0; i < 4; ++i)
#pragma unroll
            for (int j = 0; j < 8; ++j)
                acc[i][j] = __builtin_amdgcn_mfma_f32_16x16x32_bf16(
                    af[i], bfr[j], acc[i][j], 0, 0, 0);
    }

    float bv[8], gv[8];
#pragma unroll
    for (int j = 0; j < 8; ++j) {
        int col = wc * 128 + j * 16 + l16;
        bv[j] = bias[col];
        gv[j] = G2[col];
    }
    // per-row sum of squares -> LDS (each (wc, local row) slot written once)
#pragma unroll
    for (int i = 0; i < 4; ++i) {
#pragma unroll
        for (int r = 0; r < 4; ++r) {
            float s = 0.f;
#pragma unroll
            for (int j = 0; j < 8; ++j) {
                float v = acc[i][j][r] + bv[j];
                s += v * v;
            }
            s += __shfl_xor(s, 1);
            s += __shfl_xor(s, 2);
            s += __shfl_xor(s, 4);
            s += __shfl_xor(s, 8);
            if (l16 == 0)
                ssqs[wc][wr * 64 + i * 16 + quad * 4 + r] = s;
        }
    }
    __syncthreads();
#pragma unroll
    for (int i = 0; i < 4; ++i) {
#pragma unroll
        for (int r = 0; r < 4; ++r) {
            int lr = wr * 64 + i * 16 + quad * 4 + r;
            float inv = rsqrtf((ssqs[0][lr] + ssqs[1][lr]) * (1.f / N) + 1e-12f);
            float* op = out + (size_t)(rowBase + lr) * N + wc * 128 + l16;
#pragma unroll
            for (int j = 0; j < 8; ++j) {
                float v = (acc[i][j][r] + bv[j]) * gv[j] * inv;
                op[j * 16] = v > 0.f ? v : 0.f;
            }
        }
    }
}

// ---------------------------------------------------------------------------
__global__ __launch_bounds__(256) void k_invr(float* ssq, int n, float invD)
{
    int i = blockIdx.x * 256 + threadIdx.x;
    if (i < n) ssq[i] = rsqrtf(ssq[i] * invD + 1e-12f);
}

// tiled transpose + cast: in fp32 [R][C] -> out bf16 [C][R]; grid (C/32, R/32)
__global__ __launch_bounds__(256) void k_castT(
    const float* __restrict__ in, bf16* __restrict__ out, int R, int C)
{
    __shared__ float tile[32][33];
    int lx = threadIdx.x & 31, ly = threadIdx.x >> 5;
    int c0 = blockIdx.x * 32, r0 = blockIdx.y * 32;
#pragma unroll
    for (int k = 0; k < 4; ++k)
        tile[ly + 8 * k][lx] = in[(size_t)(r0 + ly + 8 * k) * C + c0 + lx];
    __syncthreads();
#pragma unroll
    for (int k = 0; k < 4; ++k)
        out[(size_t)(c0 + ly + 8 * k) * R + r0 + lx] = (bf16)tile[lx][ly + 8 * k];
}

// ---------------------------------------------------------------------------
extern "C" void kernel_launch(void* const* d_in, const int* in_sizes, int n_in,
                              void* d_out, int out_size, void* d_ws, size_t ws_size,
                              hipStream_t stream)
{
    const float* table = (const float*)d_in[0];
    const float* asim  = (const float*)d_in[1];
    const float* tsim  = (const float*)d_in[2];
    const float* adj   = (const float*)d_in[3];
    const float* W1    = (const float*)d_in[4];
    const float* b1    = (const float*)d_in[5];
    const float* g1    = (const float*)d_in[6];
    const float* W2    = (const float*)d_in[7];
    const float* b2    = (const float*)d_in[8];
    const float* g2    = (const float*)d_in[9];
    float* out = (float*)d_out;

    char* ws = (char*)d_ws;
    const size_t SZ_X = (size_t)MROWS * DIN * 2;          // 113246208 bytes
    bf16*  X    = (bf16*)ws;                               // [M,768] bf16
    bf16*  Y1   = (bf16*)(ws + SZ_X);                      // [M,768] bf16
    bf16*  W1T  = (bf16*)(ws + 2 * SZ_X);
    bf16*  W2T  = (bf16*)(ws + 2 * SZ_X + 1179648);
    float* ssq1 = (float*)(ws + 2 * SZ_X + 1179648 + 393216);

    hipMemsetAsync(ssq1, 0, (size_t)MROWS * 4, stream);
    k_castT<<<dim3(DIN / 32, DIN / 32), 256, 0, stream>>>(W1, W1T, DIN, DIN);
    k_castT<<<dim3(DOUT / 32, DIN / 32), 256, 0, stream>>>(W2, W2T, DIN, DOUT);

    k_gether1<<<dim3(8 * S, 2), 256, 0, stream>>>(table, asim, tsim, adj, X);
    k_gemm1<<<dim3((DIN / 256) * (MROWS / 256)), 512, 0, stream>>>(X, W1T, b1, Y1, ssq1);
    k_invr<<<MROWS / 256, 256, 0, stream>>>(ssq1, MROWS, 1.f / DIN);
    k_gether2<<<dim3(8 * S, 2), 256, 0, stream>>>(Y1, ssq1, g1, asim, tsim, adj, X);
    k_gemm2f<<<MROWS / 128, 256, 0, stream>>>(X, W2T, b2, g2, out);
}

// Round 4
// 628.218 us; speedup vs baseline: 1.0150x; 1.0150x over previous
//
#include <hip/hip_runtime.h>

typedef __bf16 bf16;
typedef __bf16 bf16x4 __attribute__((ext_vector_type(4)));
typedef __bf16 bf16x8 __attribute__((ext_vector_type(8)));
typedef float f32x4 __attribute__((ext_vector_type(4)));
typedef float floatx4 __attribute__((ext_vector_type(4)));

#define S 96
#define DIN 768
#define DOUT 256
#define MROWS 73728  // 8*96*96

__device__ static inline void async16(const bf16* g, bf16* l) {
    __builtin_amdgcn_global_load_lds(
        (const __attribute__((address_space(1))) void*)g,
        (__attribute__((address_space(3))) void*)l,
        16, 0, 0);
}

// ---------------------------------------------------------------------------
// gether1: X = gether(H) + H  (coefficient 2 on center row). fp32 in, bf16 out
// grid (8*S, 2); XCD-bijective swizzle (neighbor rows L2-resident).
// ---------------------------------------------------------------------------
__global__ __launch_bounds__(256) void k_gether1(
    const float* __restrict__ H, const float* __restrict__ Asim,
    const float* __restrict__ Tsim, const float* __restrict__ Adj,
    bf16* __restrict__ X)
{
    __shared__ float adjs[S];
    __shared__ float ts[S];
    __shared__ float diagf[DIN];
    int bx = blockIdx.x;
    bx = (bx & 7) * (gridDim.x >> 3) + (bx >> 3);  // 768 % 8 == 0: bijective
    int b = bx / S, l = bx % S;
    int tid = threadIdx.x;
    long row0 = (long)(b * S + l) * S;
    if (tid < S) {
        adjs[tid] = Adj[(b * S + l) * S + tid];
        ts[tid]   = Tsim[b * S + tid];
    }
    for (int i = tid; i < DIN / 4; i += 256)
        *(f32x4*)&diagf[i * 4] = *(const f32x4*)&H[(row0 + l) * DIN + i * 4];
    float a_up = (l > 0)     ? Asim[b * S + l - 1] : 0.f;
    float a_dn = (l < S - 1) ? Asim[b * S + l + 1] : 0.f;
    long du = (l > 0)     ? -(long)S * DIN : 0;
    long dd = (l < S - 1) ?  (long)S * DIN : 0;
    __syncthreads();

    int lane = tid & 63, wv = tid >> 6;
    int k0 = blockIdx.y * (S / 2);
    for (int k = k0 + wv; k < k0 + S / 2; k += 4) {
        float tl = (k > 0)     ? ts[k - 1] : 0.f;
        float tr = (k < S - 1) ? ts[k + 1] : 0.f;
        long  dl = (k > 0)     ? -(long)DIN : 0;
        long  dr = (k < S - 1) ?  (long)DIN : 0;
        float aj = adjs[k];
        const float* hrow = H + (row0 + k) * DIN;
        bf16* xrow = X + (row0 + k) * DIN;
#pragma unroll
        for (int c = 0; c < 3; ++c) {
            int col = (lane + c * 64) * 4;
            const float* hc = hrow + col;
            f32x4 vc = *(const f32x4*)hc;
            f32x4 vl = *(const f32x4*)(hc + dl);
            f32x4 vr = *(const f32x4*)(hc + dr);
            f32x4 vu = *(const f32x4*)(hc + du);
            f32x4 vd = *(const f32x4*)(hc + dd);
            bf16x4 o;
#pragma unroll
            for (int j = 0; j < 4; ++j) {
                float v = 2.f * vc[j] + aj * diagf[col + j]
                        + tl * vl[j] + tr * vr[j]
                        + a_up * vu[j] + a_dn * vd[j];
                o[j] = (bf16)v;
            }
            *(bf16x4*)&xrow[col] = o;
        }
    }
}

// ---------------------------------------------------------------------------
// gether2: sources are h1 = relu(g1 * y * invr) reconstructed on the fly.
// grid (8*S, 2); same XCD swizzle.
// ---------------------------------------------------------------------------
__global__ __launch_bounds__(256) void k_gether2(
    const bf16* __restrict__ Y, const float* __restrict__ INV,
    const float* __restrict__ G1, const float* __restrict__ Asim,
    const float* __restrict__ Tsim, const float* __restrict__ Adj,
    bf16* __restrict__ X)
{
    __shared__ float adjs[S];
    __shared__ float ts[S];
    __shared__ float diagf[DIN];
    __shared__ float g1s[DIN];
    int bx = blockIdx.x;
    bx = (bx & 7) * (gridDim.x >> 3) + (bx >> 3);
    int b = bx / S, l = bx % S;
    int tid = threadIdx.x;
    long row0 = (long)(b * S + l) * S;
    for (int i = tid; i < DIN; i += 256) g1s[i] = G1[i];
    __syncthreads();
    if (tid < S) {
        adjs[tid] = Adj[(b * S + l) * S + tid];
        ts[tid]   = Tsim[b * S + tid];
        float iv = INV[row0 + l];
        bf16x8 yv = *(const bf16x8*)&Y[(row0 + l) * DIN + tid * 8];
#pragma unroll
        for (int j = 0; j < 8; ++j) {
            float v = g1s[tid * 8 + j] * (float)yv[j] * iv;
            diagf[tid * 8 + j] = v > 0.f ? v : 0.f;
        }
    }
    float a_up = (l > 0)     ? Asim[b * S + l - 1] : 0.f;
    float a_dn = (l < S - 1) ? Asim[b * S + l + 1] : 0.f;
    long du = (l > 0)     ? -(long)S * DIN : 0;
    long dd = (l < S - 1) ?  (long)S * DIN : 0;
    int ou = (l > 0) ? -S : 0;
    int od = (l < S - 1) ? S : 0;
    __syncthreads();

    int lane = tid & 63, wv = tid >> 6;
    int k0 = blockIdx.y * (S / 2);
    for (int k = k0 + wv; k < k0 + S / 2; k += 4) {
        float tl = (k > 0)     ? ts[k - 1] : 0.f;
        float tr = (k < S - 1) ? ts[k + 1] : 0.f;
        int   ol = (k > 0)     ? -1 : 0;
        int   orr = (k < S - 1) ? 1 : 0;
        float aj = adjs[k];
        float ivc = INV[row0 + k];
        float ivl = INV[row0 + k + ol];
        float ivr = INV[row0 + k + orr];
        float ivu = INV[row0 + k + ou];
        float ivd = INV[row0 + k + od];
        const bf16* yrow = Y + (row0 + k) * DIN;
        bf16* xrow = X + (row0 + k) * DIN;
#pragma unroll
        for (int c = 0; c < 3; ++c) {
            int col = (lane + c * 64) * 4;
            const bf16* yc = yrow + col;
            bf16x4 vc = *(const bf16x4*)yc;
            bf16x4 vl = *(const bf16x4*)(yc + (long)ol * DIN);
            bf16x4 vr = *(const bf16x4*)(yc + (long)orr * DIN);
            bf16x4 vu = *(const bf16x4*)(yc + du);
            bf16x4 vd = *(const bf16x4*)(yc + dd);
            bf16x4 o;
#pragma unroll
            for (int j = 0; j < 4; ++j) {
                float g = g1s[col + j];
                float hc_ = g * (float)vc[j] * ivc; hc_ = hc_ > 0.f ? hc_ : 0.f;
                float hl_ = g * (float)vl[j] * ivl; hl_ = hl_ > 0.f ? hl_ : 0.f;
                float hr_ = g * (float)vr[j] * ivr; hr_ = hr_ > 0.f ? hr_ : 0.f;
                float hu_ = g * (float)vu[j] * ivu; hu_ = hu_ > 0.f ? hu_ : 0.f;
                float hd_ = g * (float)vd[j] * ivd; hd_ = hd_ > 0.f ? hd_ : 0.f;
                float v = 2.f * hc_ + aj * diagf[col + j]
                        + tl * hl_ + tr * hr_ + a_up * hu_ + a_dn * hd_;
                o[j] = (bf16)v;
            }
            *(bf16x4*)&xrow[col] = o;
        }
    }
}

// ---------------------------------------------------------------------------
// GEMM1: Y1[M x 768] = X @ W1T^T + b1 (bf16). 256x256/BK=64 8-wave phase
// schedule (r3). THIS ROUND: NO ATOMICS. Per-row ssq is reduced across the 4
// col-waves in-block (LDS, reusing the dead As buffer) and written ONCE per
// (colTile,row) to partial[3][MROWS] with a plain store. Theory: the 885k
// cross-XCD atomicAdds (12 hits/address, cacheline ping-pong through the
// coherence point) were the schedule-invariant cost pinning gemm1 at 148us
// across three different K-loop structures.
// ---------------------------------------------------------------------------
__global__ __launch_bounds__(512, 2) void k_gemm1(
    const bf16* __restrict__ Xm, const bf16* __restrict__ WT,
    const float* __restrict__ bias, bf16* __restrict__ Y,
    float* __restrict__ part)
{
    constexpr int K = 768, N = 768;
    constexpr int NTILE = K / 64;  // 12
    __shared__ __align__(16) bf16 As[2][256 * 64];
    __shared__ __align__(16) bf16 Bs[2][256 * 64];
    int t = threadIdx.x;
    int wg = blockIdx.x;
    wg = (wg & 7) * (gridDim.x >> 3) + (wg >> 3);  // 864 = 8*108: bijective
    int colTile = wg % 3;
    int colBase = colTile * 256;                   // col fastest within XCD
    int rowBase = (wg / 3) * 256;
    int lane = t & 63, w = t >> 6;
    int quad = lane >> 4, l16 = lane & 15;
    int wr = w >> 2, wc = w & 3;                   // 2 x 4 waves

    floatx4 acc[8][4];
#pragma unroll
    for (int i = 0; i < 8; ++i)
#pragma unroll
        for (int j = 0; j < 4; ++j) acc[i][j] = (floatx4)0.f;

    // staging: sub-stage s covers rows [s*64, s*64+64); thread t -> row tr,
    // LDS chunk (t&7); global chunk pre-swizzled gc = (t&7) ^ (row&7).
    int tr = t >> 3;
    int gc = (t & 7) ^ (tr & 7);
    const bf16* gA = Xm + (size_t)(rowBase + tr) * K + gc * 8;
    const bf16* gB = WT + (size_t)(colBase + tr) * K + gc * 8;
    int ldst = t * 8;

    auto stageA = [&](int b, int s, int kt) {
        async16(gA + (size_t)s * 64 * K + kt * 64, &As[b][s * 4096 + ldst]);
    };
    auto stageB = [&](int b, int s, int kt) {
        async16(gB + (size_t)s * 64 * K + kt * 64, &Bs[b][s * 4096 + ldst]);
    };

    // prologue: tile 0, order B0 B1 B2 B3 A0 A2 A1 A3
    stageB(0, 0, 0); stageB(0, 1, 0); stageB(0, 2, 0); stageB(0, 3, 0);
    stageA(0, 0, 0); stageA(0, 2, 0); stageA(0, 1, 0); stageA(0, 3, 0);
    asm volatile("s_waitcnt vmcnt(2)" ::: "memory");
    __builtin_amdgcn_s_barrier();

    int swz = l16 & 7;
    int cK0 = (quad ^ swz) * 8;         // chunk offset (elems), k-step 0
    int cK1 = ((quad + 4) ^ swz) * 8;   // k-step 1

    for (int tt = 0; tt < NTILE; ++tt) {
        int cur = tt & 1;
        int nb = cur ^ 1;
        bool more = (tt + 1 < NTILE);
        const bf16* aB = &As[cur][(wr * 128 + l16) * 64];
        const bf16* bB = &Bs[cur][(wc * 64 + l16) * 64];
#pragma unroll
        for (int p = 0; p < 4; ++p) {
            const int ihalf = p & 1;
            const int co = (p >> 1) ? cK1 : cK0;
            bf16x8 af[4], bfr[4];
#pragma unroll
            for (int ii = 0; ii < 4; ++ii)
                af[ii] = *(const bf16x8*)(aB + (ihalf * 4 + ii) * 1024 + co);
#pragma unroll
            for (int j = 0; j < 4; ++j)
                bfr[j] = *(const bf16x8*)(bB + j * 1024 + co);
            if (more) {
                if (p == 0) { stageB(nb, 0, tt + 1); stageB(nb, 1, tt + 1); }
                if (p == 1) { stageB(nb, 2, tt + 1); stageB(nb, 3, tt + 1); }
                if (p == 2) { stageA(nb, 0, tt + 1); stageA(nb, 2, tt + 1); }
                if (p == 3) { stageA(nb, 1, tt + 1); stageA(nb, 3, tt + 1); }
            }
            __builtin_amdgcn_s_barrier();
            asm volatile("s_waitcnt lgkmcnt(0)" ::: "memory");
            __builtin_amdgcn_sched_barrier(0);
            __builtin_amdgcn_s_setprio(1);
#pragma unroll
            for (int ii = 0; ii < 4; ++ii)
#pragma unroll
                for (int j = 0; j < 4; ++j)
                    acc[ihalf * 4 + ii][j] = __builtin_amdgcn_mfma_f32_16x16x32_bf16(
                        af[ii], bfr[j], acc[ihalf * 4 + ii][j], 0, 0, 0);
            __builtin_amdgcn_s_setprio(0);
            if (p == 0) {
                if (more) asm volatile("s_waitcnt vmcnt(2)" ::: "memory");
                else      asm volatile("s_waitcnt vmcnt(0)" ::: "memory");
            }
            if (p == 3 && more) asm volatile("s_waitcnt vmcnt(2)" ::: "memory");
            __builtin_amdgcn_s_barrier();
        }
    }

    // epilogue: Y write + in-block ssq reduction (LDS reuse of As; all waves
    // are past the final barrier, no ds_reads outstanding).
    float* ssql = (float*)&As[0][0];   // [4][256] floats = 4KB
    float bv[4];
#pragma unroll
    for (int j = 0; j < 4; ++j)
        bv[j] = bias[colBase + wc * 64 + j * 16 + l16];
#pragma unroll
    for (int i = 0; i < 8; ++i) {
#pragma unroll
        for (int r = 0; r < 4; ++r) {
            int lr = wr * 128 + i * 16 + quad * 4 + r;
            bf16* yp = Y + (size_t)(rowBase + lr) * N + colBase + wc * 64 + l16;
            float s = 0.f;
#pragma unroll
            for (int j = 0; j < 4; ++j) {
                float v = acc[i][j][r] + bv[j];
                s += v * v;
                yp[j * 16] = (bf16)v;
            }
            s += __shfl_xor(s, 1);
            s += __shfl_xor(s, 2);
            s += __shfl_xor(s, 4);
            s += __shfl_xor(s, 8);
            if (l16 == 0) ssql[wc * 256 + lr] = s;
        }
    }
    __syncthreads();
    if (t < 256) {
        float s = ssql[t] + ssql[256 + t] + ssql[512 + t] + ssql[768 + t];
        part[(size_t)colTile * MROWS + rowBase + t] = s;   // plain store, 1 writer
    }
}

// ---------------------------------------------------------------------------
// GEMM2 fused: out[M x 256] = relu(g2 * t5norm(X2 @ W2T^T + b2)) directly.
// Block covers 128 rows x ALL 256 cols; 3-buf counted vmcnt (r2 version).
// ---------------------------------------------------------------------------
__global__ __launch_bounds__(256, 2) void k_gemm2f(
    const bf16* __restrict__ Xm, const bf16* __restrict__ WT,
    const float* __restrict__ bias, const float* __restrict__ G2,
    float* __restrict__ out)
{
    constexpr int K = 768, N = 256;
    constexpr int NT = K / 32;  // 24
    __shared__ __align__(16) bf16 As[3][128 * 32];
    __shared__ __align__(16) bf16 Bs[3][256 * 32];
    __shared__ float ssqs[2][128];
    int t = threadIdx.x;
    int rowBase = blockIdx.x * 128;
    int lane = t & 63, w = t >> 6;
    int quad = lane >> 4, l16 = lane & 15;
    int wr = w >> 1, wc = w & 1;

    floatx4 acc[4][8];
#pragma unroll
    for (int i = 0; i < 4; ++i)
#pragma unroll
        for (int j = 0; j < 8; ++j) acc[i][j] = (floatx4)0.f;

    int chunk = (t & 3) ^ ((t >> 3) & 3);
    const bf16* gA = Xm + (size_t)(rowBase + (t >> 2)) * K + chunk * 8;
    const bf16* gB = WT + (size_t)(t >> 2) * K + chunk * 8;
    int l8 = t * 8;

    auto stage = [&](int buf, int kk) {
        async16(gA + kk, &As[buf][l8]);
        async16(gA + kk + 64 * K, &As[buf][l8 + 2048]);
        async16(gB + kk, &Bs[buf][l8]);
        async16(gB + kk + 64 * K, &Bs[buf][l8 + 2048]);
        async16(gB + kk + 128 * K, &Bs[buf][l8 + 4096]);
        async16(gB + kk + 192 * K, &Bs[buf][l8 + 6144]);
    };

    stage(0, 0);
    stage(1, 32);
    for (int tt = 0; tt < NT; ++tt) {
        if (tt + 1 < NT) asm volatile("s_waitcnt vmcnt(6)" ::: "memory");
        else             asm volatile("s_waitcnt vmcnt(0)" ::: "memory");
        __builtin_amdgcn_s_barrier();
        int cur = tt % 3;
        bf16x8 af[4], bfr[8];
#pragma unroll
        for (int i = 0; i < 4; ++i) {
            int ra = wr * 64 + i * 16 + l16;
            af[i] = *(const bf16x8*)&As[cur][ra * 32 + (quad ^ ((ra >> 1) & 3)) * 8];
        }
#pragma unroll
        for (int j = 0; j < 8; ++j) {
            int rb = wc * 128 + j * 16 + l16;
            bfr[j] = *(const bf16x8*)&Bs[cur][rb * 32 + (quad ^ ((rb >> 1) & 3)) * 8];
        }
        if (tt + 2 < NT) stage((tt + 2) % 3, (tt + 2) * 32);
#pragma unroll
        for (int i = 0; i < 4; ++i)
#pragma unroll
            for (int j = 0; j < 8; ++j)
                acc[i][j] = __builtin_amdgcn_mfma_f32_16x16x32_bf16(
                    af[i], bfr[j], acc[i][j], 0, 0, 0);
    }

    float bv[8], gv[8];
#pragma unroll
    for (int j = 0; j < 8; ++j) {
        int col = wc * 128 + j * 16 + l16;
        bv[j] = bias[col];
        gv[j] = G2[col];
    }
    // per-row sum of squares -> LDS (each (wc, local row) slot written once)
#pragma unroll
    for (int i = 0; i < 4; ++i) {
#pragma unroll
        for (int r = 0; r < 4; ++r) {
            float s = 0.f;
#pragma unroll
            for (int j = 0; j < 8; ++j) {
                float v = acc[i][j][r] + bv[j];
                s += v * v;
            }
            s += __shfl_xor(s, 1);
            s += __shfl_xor(s, 2);
            s += __shfl_xor(s, 4);
            s += __shfl_xor(s, 8);
            if (l16 == 0)
                ssqs[wc][wr * 64 + i * 16 + quad * 4 + r] = s;
        }
    }
    __syncthreads();
#pragma unroll
    for (int i = 0; i < 4; ++i) {
#pragma unroll
        for (int r = 0; r < 4; ++r) {
            int lr = wr * 64 + i * 16 + quad * 4 + r;
            float inv = rsqrtf((ssqs[0][lr] + ssqs[1][lr]) * (1.f / N) + 1e-12f);
            float* op = out + (size_t)(rowBase + lr) * N + wc * 128 + l16;
#pragma unroll
            for (int j = 0; j < 8; ++j) {
                float v = (acc[i][j][r] + bv[j]) * gv[j] * inv;
                op[j * 16] = v > 0.f ? v : 0.f;
            }
        }
    }
}

// ---------------------------------------------------------------------------
// sum 3 col-tile partials -> inv = rsqrt(ssq/D + eps)
__global__ __launch_bounds__(256) void k_invr(
    const float* __restrict__ part, float* __restrict__ inv, int n, float invD)
{
    int i = blockIdx.x * 256 + threadIdx.x;
    if (i < n) {
        float s = part[i] + part[n + i] + part[2 * (size_t)n + i];
        inv[i] = rsqrtf(s * invD + 1e-12f);
    }
}

// tiled transpose + cast: in fp32 [R][C] -> out bf16 [C][R]; grid (C/32, R/32)
__global__ __launch_bounds__(256) void k_castT(
    const float* __restrict__ in, bf16* __restrict__ out, int R, int C)
{
    __shared__ float tile[32][33];
    int lx = threadIdx.x & 31, ly = threadIdx.x >> 5;
    int c0 = blockIdx.x * 32, r0 = blockIdx.y * 32;
#pragma unroll
    for (int k = 0; k < 4; ++k)
        tile[ly + 8 * k][lx] = in[(size_t)(r0 + ly + 8 * k) * C + c0 + lx];
    __syncthreads();
#pragma unroll
    for (int k = 0; k < 4; ++k)
        out[(size_t)(c0 + ly + 8 * k) * R + r0 + lx] = (bf16)tile[lx][ly + 8 * k];
}

// ---------------------------------------------------------------------------
extern "C" void kernel_launch(void* const* d_in, const int* in_sizes, int n_in,
                              void* d_out, int out_size, void* d_ws, size_t ws_size,
                              hipStream_t stream)
{
    const float* table = (const float*)d_in[0];
    const float* asim  = (const float*)d_in[1];
    const float* tsim  = (const float*)d_in[2];
    const float* adj   = (const float*)d_in[3];
    const float* W1    = (const float*)d_in[4];
    const float* b1    = (const float*)d_in[5];
    const float* g1    = (const float*)d_in[6];
    const float* W2    = (const float*)d_in[7];
    const float* b2    = (const float*)d_in[8];
    const float* g2    = (const float*)d_in[9];
    float* out = (float*)d_out;

    char* ws = (char*)d_ws;
    const size_t SZ_X = (size_t)MROWS * DIN * 2;          // 113246208 bytes
    bf16*  X    = (bf16*)ws;                               // [M,768] bf16
    bf16*  Y1   = (bf16*)(ws + SZ_X);                      // [M,768] bf16
    bf16*  W1T  = (bf16*)(ws + 2 * SZ_X);
    bf16*  W2T  = (bf16*)(ws + 2 * SZ_X + 1179648);
    float* inv1 = (float*)(ws + 2 * SZ_X + 1179648 + 393216);        // [M]
    float* part = inv1 + MROWS;                                      // [3][M]

    k_castT<<<dim3(DIN / 32, DIN / 32), 256, 0, stream>>>(W1, W1T, DIN, DIN);
    k_castT<<<dim3(DOUT / 32, DIN / 32), 256, 0, stream>>>(W2, W2T, DIN, DOUT);

    k_gether1<<<dim3(8 * S, 2), 256, 0, stream>>>(table, asim, tsim, adj, X);
    k_gemm1<<<dim3((DIN / 256) * (MROWS / 256)), 512, 0, stream>>>(X, W1T, b1, Y1, part);
    k_invr<<<MROWS / 256, 256, 0, stream>>>(part, inv1, MROWS, 1.f / DIN);
    k_gether2<<<dim3(8 * S, 2), 256, 0, stream>>>(Y1, inv1, g1, asim, tsim, adj, X);
    k_gemm2f<<<MROWS / 128, 256, 0, stream>>>(X, W2T, b2, g2, out);
}

// Round 6
// 595.116 us; speedup vs baseline: 1.0714x; 1.0556x over previous
//
#include <hip/hip_runtime.h>

typedef __bf16 bf16;
typedef __bf16 bf16x4 __attribute__((ext_vector_type(4)));
typedef __bf16 bf16x8 __attribute__((ext_vector_type(8)));
typedef float f32x4 __attribute__((ext_vector_type(4)));
typedef float floatx4 __attribute__((ext_vector_type(4)));

#define S 96
#define DIN 768
#define DOUT 256
#define MROWS 73728  // 8*96*96

__device__ static inline void async16(const bf16* g, bf16* l) {
    __builtin_amdgcn_global_load_lds(
        (const __attribute__((address_space(1))) void*)g,
        (__attribute__((address_space(3))) void*)l,
        16, 0, 0);
}

// ---------------------------------------------------------------------------
// cast: fp32 -> bf16, grid-stride, 8 elems/thread/iter
// ---------------------------------------------------------------------------
__global__ __launch_bounds__(256) void k_cast(
    const float* __restrict__ in, bf16* __restrict__ out, long n)
{
    long i = ((long)blockIdx.x * 256 + threadIdx.x) * 8;
    long stride = (long)gridDim.x * 256 * 8;
    for (; i < n; i += stride) {
        f32x4 a = *(const f32x4*)&in[i];
        f32x4 b = *(const f32x4*)&in[i + 4];
        bf16x8 o;
#pragma unroll
        for (int j = 0; j < 4; ++j) { o[j] = (bf16)a[j]; o[4 + j] = (bf16)b[j]; }
        *(bf16x8*)&out[i] = o;
    }
}

// ---------------------------------------------------------------------------
// GEMM1: P0[M x 768] = X0 @ W1T^T (bf16). 256x256/BK=64, 8 waves, counted
// vmcnt, chunk-XOR swizzle. No epilogue math: gether commutes with @W1, so
// bias+gather+norm all happen downstream (gn1).
// ---------------------------------------------------------------------------
__global__ __launch_bounds__(512, 2) void k_gemm1(
    const bf16* __restrict__ Xm, const bf16* __restrict__ WT,
    bf16* __restrict__ Y)
{
    constexpr int K = 768, N = 768;
    constexpr int NTILE = K / 64;  // 12
    __shared__ __align__(16) bf16 As[2][256 * 64];
    __shared__ __align__(16) bf16 Bs[2][256 * 64];
    int t = threadIdx.x;
    int wg = blockIdx.x;
    wg = (wg & 7) * (gridDim.x >> 3) + (wg >> 3);  // 864 = 8*108: bijective
    int colBase = (wg % 3) * 256;                  // col fastest within XCD
    int rowBase = (wg / 3) * 256;
    int lane = t & 63, w = t >> 6;
    int quad = lane >> 4, l16 = lane & 15;
    int wr = w >> 2, wc = w & 3;                   // 2 x 4 waves

    floatx4 acc[8][4];
#pragma unroll
    for (int i = 0; i < 8; ++i)
#pragma unroll
        for (int j = 0; j < 4; ++j) acc[i][j] = (floatx4)0.f;

    int tr = t >> 3;
    int gc = (t & 7) ^ (tr & 7);
    const bf16* gA = Xm + (size_t)(rowBase + tr) * K + gc * 8;
    const bf16* gB = WT + (size_t)(colBase + tr) * K + gc * 8;
    int ldst = t * 8;

    auto stageA = [&](int b, int s, int kt) {
        async16(gA + (size_t)s * 64 * K + kt * 64, &As[b][s * 4096 + ldst]);
    };
    auto stageB = [&](int b, int s, int kt) {
        async16(gB + (size_t)s * 64 * K + kt * 64, &Bs[b][s * 4096 + ldst]);
    };

    // prologue: tile 0, order B0 B1 B2 B3 A0 A2 A1 A3
    stageB(0, 0, 0); stageB(0, 1, 0); stageB(0, 2, 0); stageB(0, 3, 0);
    stageA(0, 0, 0); stageA(0, 2, 0); stageA(0, 1, 0); stageA(0, 3, 0);
    asm volatile("s_waitcnt vmcnt(2)" ::: "memory");
    __builtin_amdgcn_s_barrier();

    int swz = l16 & 7;
    int cK0 = (quad ^ swz) * 8;
    int cK1 = ((quad + 4) ^ swz) * 8;

    for (int tt = 0; tt < NTILE; ++tt) {
        int cur = tt & 1;
        int nb = cur ^ 1;
        bool more = (tt + 1 < NTILE);
        const bf16* aB = &As[cur][(wr * 128 + l16) * 64];
        const bf16* bB = &Bs[cur][(wc * 64 + l16) * 64];
#pragma unroll
        for (int p = 0; p < 4; ++p) {
            const int ihalf = p & 1;
            const int co = (p >> 1) ? cK1 : cK0;
            bf16x8 af[4], bfr[4];
#pragma unroll
            for (int ii = 0; ii < 4; ++ii)
                af[ii] = *(const bf16x8*)(aB + (ihalf * 4 + ii) * 1024 + co);
#pragma unroll
            for (int j = 0; j < 4; ++j)
                bfr[j] = *(const bf16x8*)(bB + j * 1024 + co);
            if (more) {
                if (p == 0) { stageB(nb, 0, tt + 1); stageB(nb, 1, tt + 1); }
                if (p == 1) { stageB(nb, 2, tt + 1); stageB(nb, 3, tt + 1); }
                if (p == 2) { stageA(nb, 0, tt + 1); stageA(nb, 2, tt + 1); }
                if (p == 3) { stageA(nb, 1, tt + 1); stageA(nb, 3, tt + 1); }
            }
            __builtin_amdgcn_s_barrier();
            asm volatile("s_waitcnt lgkmcnt(0)" ::: "memory");
            __builtin_amdgcn_sched_barrier(0);
            __builtin_amdgcn_s_setprio(1);
#pragma unroll
            for (int ii = 0; ii < 4; ++ii)
#pragma unroll
                for (int j = 0; j < 4; ++j)
                    acc[ihalf * 4 + ii][j] = __builtin_amdgcn_mfma_f32_16x16x32_bf16(
                        af[ii], bfr[j], acc[ihalf * 4 + ii][j], 0, 0, 0);
            __builtin_amdgcn_s_setprio(0);
            if (p == 0) {
                if (more) asm volatile("s_waitcnt vmcnt(2)" ::: "memory");
                else      asm volatile("s_waitcnt vmcnt(0)" ::: "memory");
            }
            if (p == 3 && more) asm volatile("s_waitcnt vmcnt(2)" ::: "memory");
            __builtin_amdgcn_s_barrier();
        }
    }

#pragma unroll
    for (int i = 0; i < 8; ++i) {
#pragma unroll
        for (int r = 0; r < 4; ++r) {
            int row = rowBase + wr * 128 + i * 16 + quad * 4 + r;
            bf16* yp = Y + (size_t)row * N + colBase + wc * 64 + l16;
#pragma unroll
            for (int j = 0; j < 4; ++j)
                yp[j * 16] = (bf16)acc[i][j][r];
        }
    }
}

// ---------------------------------------------------------------------------
// gn1: h1 = relu(g1 * t5norm((2I+G')P0 + b1)). One (b,l,half) per block;
// each wave owns whole rows (768 elems = 12 f32/lane), ssq via shuffle
// reduce, norm+relu+cast in the same pass.
// ---------------------------------------------------------------------------
__global__ __launch_bounds__(256) void k_gn1(
    const bf16* __restrict__ P, const float* __restrict__ G1,
    const float* __restrict__ B1, const float* __restrict__ Asim,
    const float* __restrict__ Tsim, const float* __restrict__ Adj,
    bf16* __restrict__ O)
{
    __shared__ float adjs[S];
    __shared__ float ts[S];
    __shared__ float diagf[DIN];
    __shared__ float g1s[DIN];
    __shared__ float b1s[DIN];
    int bx = blockIdx.x;
    bx = (bx & 7) * (gridDim.x >> 3) + (bx >> 3);  // 768 % 8 == 0
    int b = bx / S, l = bx % S;
    int tid = threadIdx.x;
    long row0 = (long)(b * S + l) * S;
    for (int i = tid; i < DIN; i += 256) { g1s[i] = G1[i]; b1s[i] = B1[i]; }
    if (tid < S) {
        adjs[tid] = Adj[(b * S + l) * S + tid];
        ts[tid]   = Tsim[b * S + tid];
        bf16x8 dv = *(const bf16x8*)&P[(row0 + l) * DIN + tid * 8];
#pragma unroll
        for (int j = 0; j < 8; ++j) diagf[tid * 8 + j] = (float)dv[j];
    }
    float a_up = (l > 0)     ? Asim[b * S + l - 1] : 0.f;
    float a_dn = (l < S - 1) ? Asim[b * S + l + 1] : 0.f;
    long du = (l > 0)     ? -(long)S * DIN : 0;
    long dd = (l < S - 1) ?  (long)S * DIN : 0;
    __syncthreads();

    int lane = tid & 63, wv = tid >> 6;
    int k0 = blockIdx.y * (S / 2);
    for (int k = k0 + wv; k < k0 + S / 2; k += 4) {
        float tl = (k > 0)     ? ts[k - 1] : 0.f;
        float tr = (k < S - 1) ? ts[k + 1] : 0.f;
        long  dl = (k > 0)     ? -(long)DIN : 0;
        long  dr = (k < S - 1) ?  (long)DIN : 0;
        float aj = adjs[k];
        const bf16* prow = P + (row0 + k) * DIN;
        bf16* orow = O + (row0 + k) * DIN;
        float v[12];
        float ss = 0.f;
#pragma unroll
        for (int c = 0; c < 3; ++c) {
            int col = (lane + c * 64) * 4;
            const bf16* pc = prow + col;
            bf16x4 vc = *(const bf16x4*)pc;
            bf16x4 vl = *(const bf16x4*)(pc + dl);
            bf16x4 vr = *(const bf16x4*)(pc + dr);
            bf16x4 vu = *(const bf16x4*)(pc + du);
            bf16x4 vd = *(const bf16x4*)(pc + dd);
#pragma unroll
            for (int j = 0; j < 4; ++j) {
                float x = 2.f * (float)vc[j] + aj * diagf[col + j]
                        + tl * (float)vl[j] + tr * (float)vr[j]
                        + a_up * (float)vu[j] + a_dn * (float)vd[j]
                        + b1s[col + j];
                v[c * 4 + j] = x;
                ss += x * x;
            }
        }
        ss += __shfl_xor(ss, 1);
        ss += __shfl_xor(ss, 2);
        ss += __shfl_xor(ss, 4);
        ss += __shfl_xor(ss, 8);
        ss += __shfl_xor(ss, 16);
        ss += __shfl_xor(ss, 32);
        float inv = rsqrtf(ss * (1.f / DIN) + 1e-12f);
#pragma unroll
        for (int c = 0; c < 3; ++c) {
            int col = (lane + c * 64) * 4;
            bf16x4 o;
#pragma unroll
            for (int j = 0; j < 4; ++j) {
                float y = v[c * 4 + j] * g1s[col + j] * inv;
                o[j] = (bf16)(y > 0.f ? y : 0.f);
            }
            *(bf16x4*)&orow[col] = o;
        }
    }
}

// ---------------------------------------------------------------------------
// GEMM2: P1[M x 256] = h1 @ W2T^T (bf16, plain — norm moved to gn2).
// 128 rows x 256 cols per block; 3-buf counted vmcnt.
// ---------------------------------------------------------------------------
__global__ __launch_bounds__(256, 2) void k_gemm2(
    const bf16* __restrict__ Xm, const bf16* __restrict__ WT,
    bf16* __restrict__ Y)
{
    constexpr int K = 768, N = 256;
    constexpr int NT = K / 32;  // 24
    __shared__ __align__(16) bf16 As[3][128 * 32];
    __shared__ __align__(16) bf16 Bs[3][256 * 32];
    int t = threadIdx.x;
    int rowBase = blockIdx.x * 128;
    int lane = t & 63, w = t >> 6;
    int quad = lane >> 4, l16 = lane & 15;
    int wr = w >> 1, wc = w & 1;

    floatx4 acc[4][8];
#pragma unroll
    for (int i = 0; i < 4; ++i)
#pragma unroll
        for (int j = 0; j < 8; ++j) acc[i][j] = (floatx4)0.f;

    int chunk = (t & 3) ^ ((t >> 3) & 3);
    const bf16* gA = Xm + (size_t)(rowBase + (t >> 2)) * K + chunk * 8;
    const bf16* gB = WT + (size_t)(t >> 2) * K + chunk * 8;
    int l8 = t * 8;

    auto stage = [&](int buf, int kk) {
        async16(gA + kk, &As[buf][l8]);
        async16(gA + kk + 64 * K, &As[buf][l8 + 2048]);
        async16(gB + kk, &Bs[buf][l8]);
        async16(gB + kk + 64 * K, &Bs[buf][l8 + 2048]);
        async16(gB + kk + 128 * K, &Bs[buf][l8 + 4096]);
        async16(gB + kk + 192 * K, &Bs[buf][l8 + 6144]);
    };

    stage(0, 0);
    stage(1, 32);
    for (int tt = 0; tt < NT; ++tt) {
        if (tt + 1 < NT) asm volatile("s_waitcnt vmcnt(6)" ::: "memory");
        else             asm volatile("s_waitcnt vmcnt(0)" ::: "memory");
        __builtin_amdgcn_s_barrier();
        int cur = tt % 3;
        bf16x8 af[4], bfr[8];
#pragma unroll
        for (int i = 0; i < 4; ++i) {
            int ra = wr * 64 + i * 16 + l16;
            af[i] = *(const bf16x8*)&As[cur][ra * 32 + (quad ^ ((ra >> 1) & 3)) * 8];
        }
#pragma unroll
        for (int j = 0; j < 8; ++j) {
            int rb = wc * 128 + j * 16 + l16;
            bfr[j] = *(const bf16x8*)&Bs[cur][rb * 32 + (quad ^ ((rb >> 1) & 3)) * 8];
        }
        if (tt + 2 < NT) stage((tt + 2) % 3, (tt + 2) * 32);
#pragma unroll
        for (int i = 0; i < 4; ++i)
#pragma unroll
            for (int j = 0; j < 8; ++j)
                acc[i][j] = __builtin_amdgcn_mfma_f32_16x16x32_bf16(
                    af[i], bfr[j], acc[i][j], 0, 0, 0);
    }

#pragma unroll
    for (int i = 0; i < 4; ++i) {
#pragma unroll
        for (int r = 0; r < 4; ++r) {
            int row = rowBase + wr * 64 + i * 16 + quad * 4 + r;
            bf16* yp = Y + (size_t)row * N + wc * 128 + l16;
#pragma unroll
            for (int j = 0; j < 8; ++j)
                yp[j * 16] = (bf16)acc[i][j][r];
        }
    }
}

// ---------------------------------------------------------------------------
// gn2: out = relu(g2 * t5norm((2I+G')P1 + b2)), fp32 out. D=256: 4 f32/lane.
// ---------------------------------------------------------------------------
__global__ __launch_bounds__(256) void k_gn2(
    const bf16* __restrict__ P, const float* __restrict__ G2,
    const float* __restrict__ B2, const float* __restrict__ Asim,
    const float* __restrict__ Tsim, const float* __restrict__ Adj,
    float* __restrict__ O)
{
    __shared__ float adjs[S];
    __shared__ float ts[S];
    __shared__ float diagf[DOUT];
    __shared__ float g2s[DOUT];
    __shared__ float b2s[DOUT];
    int bx = blockIdx.x;
    bx = (bx & 7) * (gridDim.x >> 3) + (bx >> 3);
    int b = bx / S, l = bx % S;
    int tid = threadIdx.x;
    long row0 = (long)(b * S + l) * S;
    if (tid < DOUT) { g2s[tid] = G2[tid]; b2s[tid] = B2[tid]; }
    if (tid < S) {
        adjs[tid] = Adj[(b * S + l) * S + tid];
        ts[tid]   = Tsim[b * S + tid];
    }
    if (tid < 32) {
        bf16x8 dv = *(const bf16x8*)&P[(row0 + l) * DOUT + tid * 8];
#pragma unroll
        for (int j = 0; j < 8; ++j) diagf[tid * 8 + j] = (float)dv[j];
    }
    float a_up = (l > 0)     ? Asim[b * S + l - 1] : 0.f;
    float a_dn = (l < S - 1) ? Asim[b * S + l + 1] : 0.f;
    long du = (l > 0)     ? -(long)S * DOUT : 0;
    long dd = (l < S - 1) ?  (long)S * DOUT : 0;
    __syncthreads();

    int lane = tid & 63, wv = tid >> 6;
    int k0 = blockIdx.y * (S / 2);
    for (int k = k0 + wv; k < k0 + S / 2; k += 4) {
        float tl = (k > 0)     ? ts[k - 1] : 0.f;
        float tr = (k < S - 1) ? ts[k + 1] : 0.f;
        long  dl = (k > 0)     ? -(long)DOUT : 0;
        long  dr = (k < S - 1) ?  (long)DOUT : 0;
        float aj = adjs[k];
        const bf16* prow = P + (row0 + k) * DOUT;
        float* orow = O + (row0 + k) * DOUT;
        int col = lane * 4;
        const bf16* pc = prow + col;
        bf16x4 vc = *(const bf16x4*)pc;
        bf16x4 vl = *(const bf16x4*)(pc + dl);
        bf16x4 vr = *(const bf16x4*)(pc + dr);
        bf16x4 vu = *(const bf16x4*)(pc + du);
        bf16x4 vd = *(const bf16x4*)(pc + dd);
        float v[4];
        float ss = 0.f;
#pragma unroll
        for (int j = 0; j < 4; ++j) {
            float x = 2.f * (float)vc[j] + aj * diagf[col + j]
                    + tl * (float)vl[j] + tr * (float)vr[j]
                    + a_up * (float)vu[j] + a_dn * (float)vd[j]
                    + b2s[col + j];
            v[j] = x;
            ss += x * x;
        }
        ss += __shfl_xor(ss, 1);
        ss += __shfl_xor(ss, 2);
        ss += __shfl_xor(ss, 4);
        ss += __shfl_xor(ss, 8);
        ss += __shfl_xor(ss, 16);
        ss += __shfl_xor(ss, 32);
        float inv = rsqrtf(ss * (1.f / DOUT) + 1e-12f);
        f32x4 o;
#pragma unroll
        for (int j = 0; j < 4; ++j) {
            float y = v[j] * g2s[col + j] * inv;
            o[j] = y > 0.f ? y : 0.f;
        }
        *(f32x4*)&orow[col] = o;
    }
}

// tiled transpose + cast: in fp32 [R][C] -> out bf16 [C][R]; grid (C/32, R/32)
__global__ __launch_bounds__(256) void k_castT(
    const float* __restrict__ in, bf16* __restrict__ out, int R, int C)
{
    __shared__ float tile[32][33];
    int lx = threadIdx.x & 31, ly = threadIdx.x >> 5;
    int c0 = blockIdx.x * 32, r0 = blockIdx.y * 32;
#pragma unroll
    for (int k = 0; k < 4; ++k)
        tile[ly + 8 * k][lx] = in[(size_t)(r0 + ly + 8 * k) * C + c0 + lx];
    __syncthreads();
#pragma unroll
    for (int k = 0; k < 4; ++k)
        out[(size_t)(c0 + ly + 8 * k) * R + r0 + lx] = (bf16)tile[lx][ly + 8 * k];
}

// ---------------------------------------------------------------------------
extern "C" void kernel_launch(void* const* d_in, const int* in_sizes, int n_in,
                              void* d_out, int out_size, void* d_ws, size_t ws_size,
                              hipStream_t stream)
{
    const float* table = (const float*)d_in[0];
    const float* asim  = (const float*)d_in[1];
    const float* tsim  = (const float*)d_in[2];
    const float* adj   = (const float*)d_in[3];
    const float* W1    = (const float*)d_in[4];
    const float* b1    = (const float*)d_in[5];
    const float* g1    = (const float*)d_in[6];
    const float* W2    = (const float*)d_in[7];
    const float* b2    = (const float*)d_in[8];
    const float* g2    = (const float*)d_in[9];
    float* out = (float*)d_out;

    char* ws = (char*)d_ws;
    const size_t SZ_X = (size_t)MROWS * DIN * 2;          // 113246208 bytes
    bf16*  A    = (bf16*)ws;                               // X0, later h1
    bf16*  Bb   = (bf16*)(ws + SZ_X);                      // P0, later P1
    bf16*  W1T  = (bf16*)(ws + 2 * SZ_X);
    bf16*  W2T  = (bf16*)(ws + 2 * SZ_X + 1179648);

    k_castT<<<dim3(DIN / 32, DIN / 32), 256, 0, stream>>>(W1, W1T, DIN, DIN);
    k_castT<<<dim3(DOUT / 32, DIN / 32), 256, 0, stream>>>(W2, W2T, DIN, DOUT);

    k_cast<<<2048, 256, 0, stream>>>(table, A, (long)MROWS * DIN);
    k_gemm1<<<dim3((DIN / 256) * (MROWS / 256)), 512, 0, stream>>>(A, W1T, Bb);
    k_gn1<<<dim3(8 * S, 2), 256, 0, stream>>>(Bb, g1, b1, asim, tsim, adj, A);
    k_gemm2<<<MROWS / 128, 256, 0, stream>>>(A, W2T, Bb);
    k_gn2<<<dim3(8 * S, 2), 256, 0, stream>>>(Bb, g2, b2, asim, tsim, adj, out);
}